// Round 1
// baseline (154.646 us; speedup 1.0000x reference)
//
#include <hip/hip_runtime.h>
#include <hip/hip_bf16.h>

#define B_ 4
#define N_ 4096
#define C_ 64

constexpr float LOG2E = 1.44269504088896340736f;

typedef __attribute__((ext_vector_type(8))) short short8;
typedef __attribute__((ext_vector_type(4))) float f32x4;

#if __has_builtin(__builtin_amdgcn_exp2f)
#define EXP2F(x) __builtin_amdgcn_exp2f(x)
#else
#define EXP2F(x) exp2f(x)
#endif

static __device__ inline short f32_to_bf16_bits(float f) {
    union { __hip_bfloat16 h; unsigned short u; } cv;
    cv.h = __float2bfloat16(f);
    return (short)cv.u;
}

// ---------------------------------------------------------------------------
// Kernel S: s1[b,i] = (h[b,i,:] @ a1) * log2e ; s2 likewise with a2.
// One wave per row; lane = channel c.
// ---------------------------------------------------------------------------
__global__ __launch_bounds__(256) void gat_prep_s(
    const float* __restrict__ h, const float* __restrict__ a,
    float* __restrict__ s1s, float* __restrict__ s2s)
{
    const int wave = threadIdx.x >> 6;
    const int lane = threadIdx.x & 63;
    const int row = blockIdx.x * 4 + wave;      // 0 .. B*N-1
    float hv = h[(size_t)row * C_ + lane];
    float p1 = hv * a[lane];
    float p2 = hv * a[C_ + lane];
#pragma unroll
    for (int o = 32; o >= 1; o >>= 1) {
        p1 += __shfl_xor(p1, o, 64);
        p2 += __shfl_xor(p2, o, 64);
    }
    if (lane == 0) {
        s1s[row] = p1 * LOG2E;
        s2s[row] = p2 * LOG2E;
    }
}

// ---------------------------------------------------------------------------
// Kernel T: h_t[b][c][j] = bf16(h[b][j][c])   (transpose + convert)
// One block per (b, 64-row i-tile). LDS tile with +1 pad.
// ---------------------------------------------------------------------------
__global__ __launch_bounds__(256) void gat_prep_t(
    const float* __restrict__ h, unsigned short* __restrict__ hT)
{
    const int bid = blockIdx.x;                 // B * N/64 = 256
    const int b = bid >> 6;
    const int i0 = (bid & 63) * 64;
    __shared__ float tile[64][65];
    const int t = threadIdx.x;
    {
        const int rr = t >> 2;                  // local row (j)
        const int cc = (t & 3) * 16;            // channel chunk
        const float* src = h + ((size_t)(b * N_ + i0 + rr)) * C_ + cc;
#pragma unroll
        for (int k = 0; k < 16; k += 4) {
            float4 v = *(const float4*)(src + k);
            tile[rr][cc + k + 0] = v.x;
            tile[rr][cc + k + 1] = v.y;
            tile[rr][cc + k + 2] = v.z;
            tile[rr][cc + k + 3] = v.w;
        }
    }
    __syncthreads();
    {
        const int c  = t >> 2;                  // channel
        const int ic = (t & 3) * 16;            // j chunk
        short8 w0, w1;
#pragma unroll
        for (int k = 0; k < 8; ++k)
            w0[k] = f32_to_bf16_bits(tile[ic + k][c]);
#pragma unroll
        for (int k = 0; k < 8; ++k)
            w1[k] = f32_to_bf16_bits(tile[ic + 8 + k][c]);
        unsigned short* dst = hT + ((size_t)(b * C_ + c)) * N_ + i0 + ic;
        *(short8*)(dst)     = w0;
        *(short8*)(dst + 8) = w1;
    }
}

// ---------------------------------------------------------------------------
// Main kernel: flash-style masked-softmax + PV, fixed zero max reference.
// Grid: 64 i-tile-blocks * jsNum j-splits. Block: 4 waves = 4 batches.
// Each wave: 64 rows (4 MFMA i-tiles) x full C (4 c-tiles), j-range N/jsNum.
// ---------------------------------------------------------------------------
__global__ __launch_bounds__(256) void gat_main(
    const float* __restrict__ adj, const float* __restrict__ s1s,
    const float* __restrict__ s2s, const unsigned short* __restrict__ hT,
    float* __restrict__ accP, float* __restrict__ lP, int jsNum)
{
    const int bid  = blockIdx.x;
    const int itb  = bid / jsNum;               // 0..63
    const int js   = bid % jsNum;
    const int jlen = N_ / jsNum;
    const int j0   = js * jlen;
    const int i0   = itb * 64;
    const int wave = threadIdx.x >> 6;
    const int lane = threadIdx.x & 63;
    const int b    = wave;                      // one batch per wave
    const int g    = lane >> 4;
    const int r16  = lane & 15;

    float s1v[4];
#pragma unroll
    for (int it = 0; it < 4; ++it)
        s1v[it] = s1s[b * N_ + i0 + it * 16 + r16];

    f32x4 acc[4][4];
#pragma unroll
    for (int it = 0; it < 4; ++it)
#pragma unroll
        for (int ct = 0; ct < 4; ++ct)
            acc[it][ct] = (f32x4){0.f, 0.f, 0.f, 0.f};
    float lpart[4] = {0.f, 0.f, 0.f, 0.f};

    const unsigned short* hTb = hT + (size_t)b * C_ * N_;
    const float* s2b = s2s + b * N_;

    for (int jj = 0; jj < jlen; jj += 32) {
        const int kb = j0 + jj + g * 8;         // this lane-group's k base

        short8 bfrag[4];
#pragma unroll
        for (int ct = 0; ct < 4; ++ct)
            bfrag[ct] = *(const short8*)(hTb + (size_t)(ct * 16 + r16) * N_ + kb);

        float4 s2a = *(const float4*)(s2b + kb);
        float4 s2c = *(const float4*)(s2b + kb + 4);
        float s2v[8] = {s2a.x, s2a.y, s2a.z, s2a.w, s2c.x, s2c.y, s2c.z, s2c.w};

#pragma unroll
        for (int it = 0; it < 4; ++it) {
            const float* arow = adj + (size_t)(i0 + it * 16 + r16) * N_ + kb;
            float4 a0 = *(const float4*)(arow);
            float4 a1 = *(const float4*)(arow + 4);
            float adjv[8] = {a0.x, a0.y, a0.z, a0.w, a1.x, a1.y, a1.z, a1.w};

            const float s1 = s1v[it];
            short8 afrag;
#pragma unroll
            for (int q = 0; q < 8; ++q) {
                float e = s1 + s2v[q];
                e = fmaxf(e, 0.2f * e);          // leaky relu (scale-invariant)
                float p = (adjv[q] > 0.5f) ? EXP2F(e) : 0.0f;
                lpart[it] += p;
                afrag[q] = f32_to_bf16_bits(p);
            }
#pragma unroll
            for (int ct = 0; ct < 4; ++ct)
                acc[it][ct] = __builtin_amdgcn_mfma_f32_16x16x32_bf16(
                    afrag, bfrag[ct], acc[it][ct], 0, 0, 0);
        }
    }

    // l: sum the 4 lane-groups (each covered a distinct k-slice)
#pragma unroll
    for (int it = 0; it < 4; ++it) {
        float v = lpart[it];
        v += __shfl_xor(v, 16, 64);
        v += __shfl_xor(v, 32, 64);
        lpart[it] = v;
    }

    const size_t pb = (size_t)js * B_ + b;
    if (g == 0) {
#pragma unroll
        for (int it = 0; it < 4; ++it)
            lP[pb * N_ + i0 + it * 16 + r16] = lpart[it];
    }

    float* accBase = accP + pb * (size_t)N_ * C_;
#pragma unroll
    for (int it = 0; it < 4; ++it)
#pragma unroll
        for (int ct = 0; ct < 4; ++ct)
#pragma unroll
            for (int r = 0; r < 4; ++r) {
                const int i = i0 + it * 16 + g * 4 + r;
                const int c = ct * 16 + r16;
                accBase[(size_t)i * C_ + c] = acc[it][ct][r];
            }
}

// ---------------------------------------------------------------------------
// Combine: out = elu( (sum_p acc_p) / (sum_p l_p) )
// ---------------------------------------------------------------------------
__global__ __launch_bounds__(256) void gat_combine(
    const float* __restrict__ accP, const float* __restrict__ lP,
    float* __restrict__ out, int jsNum)
{
    const int t = blockIdx.x * 256 + threadIdx.x;
    if (t >= B_ * N_ * C_) return;
    const int bi = t / C_;
    float asum = 0.f, lsum = 0.f;
    for (int p = 0; p < jsNum; ++p) {
        asum += accP[(size_t)p * (B_ * N_ * C_) + t];
        lsum += lP[(size_t)p * (B_ * N_) + bi];
    }
    const float x = asum / lsum;
    out[t] = (x > 0.f) ? x : (expf(x) - 1.f);
}

// ---------------------------------------------------------------------------
extern "C" void kernel_launch(void* const* d_in, const int* in_sizes, int n_in,
                              void* d_out, int out_size, void* d_ws, size_t ws_size,
                              hipStream_t stream)
{
    const float* h   = (const float*)d_in[0];   // (B,N,C) f32
    const float* adj = (const float*)d_in[1];   // (N,N)   f32
    const float* a   = (const float*)d_in[2];   // (2C,1)  f32
    float* out = (float*)d_out;

    char* ws = (char*)d_ws;
    float* s1s = (float*)ws;                                    // B*N f32
    float* s2s = (float*)(ws + (size_t)B_ * N_ * 4);            // B*N f32
    unsigned short* hT = (unsigned short*)(ws + (size_t)2 * B_ * N_ * 4);
    const size_t lOff = (size_t)2 * B_ * N_ * 4 + (size_t)B_ * C_ * N_ * 2;

    int jsNum = 8;
    while (jsNum > 1) {
        size_t need = lOff + (size_t)jsNum * B_ * N_ * 4
                           + (size_t)jsNum * B_ * N_ * C_ * 4;
        if (need <= ws_size) break;
        jsNum >>= 1;
    }
    float* lP   = (float*)(ws + lOff);
    float* accP = (float*)(ws + lOff + (size_t)jsNum * B_ * N_ * 4);

    gat_prep_s<<<B_ * N_ / 4, 256, 0, stream>>>(h, a, s1s, s2s);
    gat_prep_t<<<B_ * (N_ / 64), 256, 0, stream>>>(h, hT);
    gat_main<<<64 * jsNum, 256, 0, stream>>>(adj, s1s, s2s, hT, accP, lP, jsNum);
    gat_combine<<<(B_ * N_ * C_ + 255) / 256, 256, 0, stream>>>(accP, lP, out, jsNum);
}